// Round 3
// baseline (7186.237 us; speedup 1.0000x reference)
//
#include <hip/hip_runtime.h>
#include <stdint.h>

#define SEQ 48
#define NL  16
#define NV  32000
#define POLLMAX 4000000

typedef short bf16x8 __attribute__((ext_vector_type(8)));
typedef float f32x4  __attribute__((ext_vector_type(4)));

__device__ __forceinline__ unsigned short f2b(float f) {
    union { float f; unsigned int u; } v; v.f = f;
    unsigned int r = (v.u + 0x7FFFu + ((v.u >> 16) & 1u)) >> 16;
    return (unsigned short)r;
}
__device__ __forceinline__ float b2f(unsigned short s) {
    union { float f; unsigned int u; } v; v.u = ((unsigned int)s) << 16;
    return v.f;
}
__device__ __forceinline__ bf16x8 load_w8(const float* p) {
    const float4* q = (const float4*)p;
    float4 a = q[0], b = q[1];
    bf16x8 r;
    r[0] = (short)f2b(a.x); r[1] = (short)f2b(a.y);
    r[2] = (short)f2b(a.z); r[3] = (short)f2b(a.w);
    r[4] = (short)f2b(b.x); r[5] = (short)f2b(b.y);
    r[6] = (short)f2b(b.z); r[7] = (short)f2b(b.w);
    return r;
}
__device__ __forceinline__ bf16x8 load_b8(const unsigned short* p) {
    return *(const bf16x8*)p;
}
__device__ __forceinline__ f32x4 mfma16(bf16x8 a, bf16x8 b, f32x4 c) {
    return __builtin_amdgcn_mfma_f32_16x16x32_bf16(a, b, c, 0, 0, 0);
}
__device__ __forceinline__ float sigm(float x) { return 1.0f / (1.0f + __expf(-x)); }
__device__ __forceinline__ float tanh_(float x) { return 1.0f - 2.0f / (__expf(2.0f * x) + 1.0f); }

// ---------------- embeddings: gather + bf16 ----------------
__global__ __launch_bounds__(256) void embed_kernel(
    const int* __restrict__ x, const int* __restrict__ y,
    const float* __restrict__ enc_emb, const float* __restrict__ dec_emb,
    unsigned short* __restrict__ xs, unsigned short* __restrict__ ds)
{
    int bid = blockIdx.x;             // 0..1535
    int which = bid >= 768;
    int r = which ? bid - 768 : bid;
    int t = r >> 4, b = r & 15;
    int tok = which ? y[b * SEQ + t] : x[b * SEQ + t];
    const float* src = (which ? dec_emb : enc_emb) + (size_t)tok * 512;
    unsigned short* dst = (which ? ds : xs) + ((size_t)t * 16 + b) * 512;
    for (int k = threadIdx.x; k < 512; k += 256) dst[k] = f2b(src[k]);
}

// ---------------- W_hh fp32 -> bf16 (once, grid-parallel) ----------------
__global__ __launch_bounds__(256) void wconv(
    const float* __restrict__ src, unsigned short* __restrict__ dst, int n4)
{
    int i = blockIdx.x * 256 + threadIdx.x;
    const int stride = gridDim.x * 256;
    for (; i < n4; i += stride) {
        float4 v = ((const float4*)src)[i];
        uint2 o;
        o.x = (unsigned)f2b(v.x) | ((unsigned)f2b(v.y) << 16);
        o.y = (unsigned)f2b(v.z) | ((unsigned)f2b(v.w) << 16);
        ((uint2*)dst)[i] = o;
    }
}

// ---------------- encoder v4: 256-thread WGs (1 wave/SIMD -> 512-reg budget) ----
// bid 0..15 : Stage A producers (Wih @ x + bias -> Gx). wave = gate, 2 row-tiles.
// bid 16,17 : recurrence WG, one per direction, 4 waves. Whole Whh [1024x256]
//   bf16 resident on ONE CU: 93 frags/lane in regs (372 VGPR, static-indexed),
//   35 frag-groups in 140 KB LDS. h double-buffered in LDS -> 1 barrier/step.
//   acc starts 0; Gx added in epilogue (no load->MFMA dependency).
// Per-lane budget: 372 w + 32 acc + 16 c + ~40 misc ~= 460 <= 512 (1 wave/SIMD).
// Round-2 failure: 512-thread WG forces 2 waves/SIMD -> 256 unified cap -> spills
// (VGPR_Count=128, 210 MB scratch). 256-thread WG is the only shape that fits.

__global__ __launch_bounds__(256, 1) void enc_v4(
    const float* __restrict__ Wih,             // [NL][2][1024][512] fp32
    const unsigned short* __restrict__ whhb,   // [NL][2][1024][256] bf16
    const float* __restrict__ bias,            // [NL][2][1024]
    unsigned short* __restrict__ xsA, unsigned short* __restrict__ xsB, // [48][16][512]
    unsigned short* __restrict__ dec_h0,       // [NL][16][512] bf16
    float* __restrict__ dec_c0,                // [NL][16][512] fp32
    float* __restrict__ Gx,                    // [2 par][2 dir][48][16][1024] fp32
    int* __restrict__ recflag,                 // [NL][2] stride 16 ints
    int* __restrict__ gxflag)                  // [NL][2][8] stride 16 ints
{
    const int tid = threadIdx.x, bid = blockIdx.x;
    const int wv = tid >> 6, lane = tid & 63, q = lane >> 4, ln = lane & 15;

    // LDS: 143,360 B weight/x_sh union + 16,896 B h double-buffer = 160,256 B
    __shared__ __align__(16) char smem_u[35 * 4096];
    __shared__ unsigned short h_lds2[2][16][264];

    if (bid < 16) {
        // ================= Stage A: input-GEMM producers =================
        const int dir = bid >> 3, pblk = bid & 7;
        const int cb = tid >> 4, cc = tid & 15;
        unsigned short (*x_sh)[528] = (unsigned short (*)[528])smem_u;
        for (int l = 0; l < NL; ++l) {
            bf16x8 aih[2][16];
            float4 bias4[2];
#pragma unroll
            for (int rt = 0; rt < 2; ++rt) {
                const int row0 = wv * 256 + pblk * 32 + rt * 16;
                const float* wb = Wih + (((size_t)(l * 2 + dir) * 1024) + row0 + ln) * 512;
#pragma unroll
                for (int kt = 0; kt < 16; ++kt) aih[rt][kt] = load_w8(wb + kt * 32 + q * 8);
                bias4[rt] = *(const float4*)(bias + (size_t)(l * 2 + dir) * 1024 + row0 + q * 4);
            }
            const unsigned short* xin = (l & 1) ? xsB : xsA;
            float* gxl = Gx + (size_t)((l & 1) * 2 + dir) * SEQ * 16 * 1024;
            int* myflag = gxflag + ((l * 2 + dir) * 8 + pblk) * 16;
            const int* rfprev = recflag + (l - 1) * 2 * 16;
            int seen = 0;
            for (int s = 0; s < SEQ; ++s) {
                const int t_src = dir ? (SEQ - 1 - s) : s;
                if (l > 0) {
                    // xs_l[t_src] full <=> own-dir rec(l-1) >= s+1 AND other >= 48-s
                    if (tid < 64) {
                        if (tid < 2) {
                            const int need = (tid == dir) ? (s + 1) : (SEQ - s);
                            if (seen < need) {
                                const int* f = rfprev + tid * 16;
                                int v = __hip_atomic_load(f, __ATOMIC_RELAXED, __HIP_MEMORY_SCOPE_AGENT);
                                int it = 0;
                                while (v < need && ++it <= POLLMAX)
                                    v = __hip_atomic_load(f, __ATOMIC_RELAXED, __HIP_MEMORY_SCOPE_AGENT);
                                seen = v;
                            }
                        }
                        __builtin_amdgcn_fence(__ATOMIC_ACQUIRE, "agent");
                    }
                    __syncthreads();
                }
                // stage x row into LDS
                {
                    const unsigned short* sr = xin + ((size_t)t_src * 16 + cb) * 512 + cc * 32;
#pragma unroll
                    for (int j = 0; j < 4; ++j)
                        *(bf16x8*)&x_sh[cb][cc * 32 + j * 8] = load_b8(sr + j * 8);
                }
                __syncthreads();
                f32x4 a0 = {0.f,0.f,0.f,0.f}, a1 = {0.f,0.f,0.f,0.f};
                f32x4 b0 = {0.f,0.f,0.f,0.f}, b1 = {0.f,0.f,0.f,0.f};
#pragma unroll
                for (int kt = 0; kt < 16; kt += 2) {
                    bf16x8 x0 = load_b8(&x_sh[ln][kt * 32 + q * 8]);
                    bf16x8 x1 = load_b8(&x_sh[ln][(kt + 1) * 32 + q * 8]);
                    a0 = mfma16(aih[0][kt],     x0, a0);
                    a1 = mfma16(aih[0][kt + 1], x1, a1);
                    b0 = mfma16(aih[1][kt],     x0, b0);
                    b1 = mfma16(aih[1][kt + 1], x1, b1);
                }
#pragma unroll
                for (int rt = 0; rt < 2; ++rt) {
                    const int row0 = wv * 256 + pblk * 32 + rt * 16;
                    float g0 = (rt ? b0[0] : a0[0]) + (rt ? b1[0] : a1[0]) + ((const float*)&bias4[rt])[0];
                    float g1 = (rt ? b0[1] : a0[1]) + (rt ? b1[1] : a1[1]) + ((const float*)&bias4[rt])[1];
                    float g2 = (rt ? b0[2] : a0[2]) + (rt ? b1[2] : a1[2]) + ((const float*)&bias4[rt])[2];
                    float g3 = (rt ? b0[3] : a0[3]) + (rt ? b1[3] : a1[3]) + ((const float*)&bias4[rt])[3];
                    unsigned long long u0 = (unsigned long long)__float_as_uint(g0) |
                                            ((unsigned long long)__float_as_uint(g1) << 32);
                    unsigned long long u1 = (unsigned long long)__float_as_uint(g2) |
                                            ((unsigned long long)__float_as_uint(g3) << 32);
                    unsigned long long* gd =
                        (unsigned long long*)(gxl + ((size_t)t_src * 16 + ln) * 1024 + row0 + q * 4);
                    __hip_atomic_store(gd,     u0, __ATOMIC_RELAXED, __HIP_MEMORY_SCOPE_AGENT);
                    __hip_atomic_store(gd + 1, u1, __ATOMIC_RELAXED, __HIP_MEMORY_SCOPE_AGENT);
                }
                __syncthreads();   // x_sh reads done before next chunk's writes
                if (tid == 0)
                    __hip_atomic_store(myflag, s + 1, __ATOMIC_RELEASE, __HIP_MEMORY_SCOPE_AGENT);
            }
        }
        return;
    }

    // ================= recurrence: one WG (4 waves) per direction =================
    const int dir = bid - 16;
    // frag group g layout: kt5 -> g=rt (0..15); kt6 -> g=16+rt; kt7 rt<3 -> g=32+rt
#define LDSFRAG(g) load_b8((const unsigned short*)(smem_u + (g) * 4096 + tid * 16))

    float cr[4][4];
    for (int l = 0; l < NL; ++l) {
        __syncthreads();   // prior layer's LDS-frag reads done before overwrite
        bf16x8 wreg[16][5];
        bf16x8 wk7[13];
        {
            const unsigned short* wbase = whhb + (size_t)(l * 2 + dir) * 262144;
#pragma unroll
            for (int rt = 0; rt < 16; ++rt) {
                const int row = (rt >> 2) * 256 + wv * 64 + (rt & 3) * 16 + ln;
                const unsigned short* rp = wbase + (size_t)row * 256 + q * 8;
#pragma unroll
                for (int kt = 0; kt < 5; ++kt) wreg[rt][kt] = load_b8(rp + kt * 32);
                *(bf16x8*)(smem_u + (0 * 16 + rt) * 4096 + tid * 16) = load_b8(rp + 5 * 32);
                *(bf16x8*)(smem_u + (1 * 16 + rt) * 4096 + tid * 16) = load_b8(rp + 6 * 32);
                if (rt < 3)
                    *(bf16x8*)(smem_u + (32 + rt) * 4096 + tid * 16) = load_b8(rp + 7 * 32);
                else
                    wk7[rt - 3] = load_b8(rp + 7 * 32);
            }
        }
        const int* gxf = gxflag + (l * 2 + dir) * 8 * 16;
        int* rf = recflag + (l * 2 + dir) * 16;
        const float* gxl = Gx + (size_t)((l & 1) * 2 + dir) * SEQ * 16 * 1024;
        unsigned short* xout = (l & 1) ? xsA : xsB;
        int seen = 0;

        for (int t = 0; t < SEQ; ++t) {
            const int t_src = dir ? (SEQ - 1 - t) : t;
            // wait Gx chunk t from this direction's 8 producers (value-cached)
            if (tid < 64) {
                if (tid < 8 && seen < t + 1) {
                    const int* f = gxf + tid * 16;
                    int v = __hip_atomic_load(f, __ATOMIC_RELAXED, __HIP_MEMORY_SCOPE_AGENT);
                    int it = 0;
                    while (v < t + 1 && ++it <= POLLMAX)
                        v = __hip_atomic_load(f, __ATOMIC_RELAXED, __HIP_MEMORY_SCOPE_AGENT);
                    seen = v;
                }
                __builtin_amdgcn_fence(__ATOMIC_ACQUIRE, "agent");
            }
            __syncthreads();   // also: h_lds2 writes of t-1 visible; weight LDS ready
            if (tid == 0 && t > 0)
                __hip_atomic_store(rf, t, __ATOMIC_RELEASE, __HIP_MEMORY_SCOPE_AGENT);

            const unsigned short* hcur = &h_lds2[t & 1][0][0];
            unsigned short*       hnxt = &h_lds2[(t + 1) & 1][0][0];
            const float* gxt = gxl + ((size_t)t_src * 16 + ln) * 1024;

#pragma unroll
            for (int ph = 0; ph < 2; ++ph) {
                f32x4 acc[8];
#pragma unroll
                for (int a = 0; a < 8; ++a) acc[a] = (f32x4){0.f, 0.f, 0.f, 0.f};
                if (t > 0) {
#pragma unroll
                    for (int kt = 0; kt < 8; ++kt) {
                        bf16x8 hf = load_b8(hcur + ln * 264 + kt * 32 + q * 8);
#pragma unroll
                        for (int gate = 0; gate < 4; ++gate) {
#pragma unroll
                            for (int s = 0; s < 2; ++s) {
                                const int rt = gate * 4 + ph * 2 + s;
                                bf16x8 w;
                                if (kt < 5)       w = wreg[rt][kt];
                                else if (kt < 7)  w = LDSFRAG((kt - 5) * 16 + rt);
                                else if (rt < 3)  w = LDSFRAG(32 + rt);
                                else              w = wk7[rt - 3];
                                acc[gate * 2 + s] = mfma16(w, hf, acc[gate * 2 + s]);
                            }
                        }
                    }
                }
                // epilogue: add Gx, lane-local LSTM update
#pragma unroll
                for (int s = 0; s < 2; ++s) {
                    const int u16i = ph * 2 + s;
                    const int ubase = wv * 64 + u16i * 16 + q * 4;
                    float4 gxi = *(const float4*)(gxt + 0 * 256 + ubase);
                    float4 gxf4 = *(const float4*)(gxt + 1 * 256 + ubase);
                    float4 gxg = *(const float4*)(gxt + 2 * 256 + ubase);
                    float4 gxo = *(const float4*)(gxt + 3 * 256 + ubase);
                    unsigned short hb[4];
#pragma unroll
                    for (int r = 0; r < 4; ++r) {
                        float gi = acc[0 + s][r] + ((const float*)&gxi)[r];
                        float gf = acc[2 + s][r] + ((const float*)&gxf4)[r];
                        float gg = acc[4 + s][r] + ((const float*)&gxg)[r];
                        float go = acc[6 + s][r] + ((const float*)&gxo)[r];
                        float c  = (t == 0) ? 0.f : cr[u16i][r];
                        float cn = sigm(gf) * c + sigm(gi) * tanh_(gg);
                        cr[u16i][r] = cn;
                        hb[r] = f2b(sigm(go) * tanh_(cn));
                    }
                    uint2 hv;
                    hv.x = (unsigned)hb[0] | ((unsigned)hb[1] << 16);
                    hv.y = (unsigned)hb[2] | ((unsigned)hb[3] << 16);
                    *(uint2*)(hnxt + ln * 264 + ubase) = hv;
                    unsigned long long hl = (unsigned long long)hv.x | ((unsigned long long)hv.y << 32);
                    __hip_atomic_store(
                        (unsigned long long*)(xout + ((size_t)t_src * 16 + ln) * 512 + dir * 256 + ubase),
                        hl, __ATOMIC_RELAXED, __HIP_MEMORY_SCOPE_AGENT);
                    if (t == SEQ - 1) {
                        *(uint2*)(dec_h0 + ((size_t)l * 16 + ln) * 512 + dir * 256 + ubase) = hv;
                        float4 cv;
                        cv.x = cr[u16i][0]; cv.y = cr[u16i][1];
                        cv.z = cr[u16i][2]; cv.w = cr[u16i][3];
                        *(float4*)(dec_c0 + ((size_t)l * 16 + ln) * 512 + dir * 256 + ubase) = cv;
                    }
                }
            }
        }
        __syncthreads();
        if (tid == 0)
            __hip_atomic_store(rf, SEQ, __ATOMIC_RELEASE, __HIP_MEMORY_SCOPE_AGENT);
    }
#undef LDSFRAG
}

// ---------------- pipelined decoder: ALL 16 layers concurrent, 512 WGs ----------------
__global__ __launch_bounds__(256, 2) void dec_pipe(
    const float* __restrict__ Wih,   // [NL][2048][512]
    const float* __restrict__ Whh,   // [NL][2048][512]
    const float* __restrict__ bias,  // [NL][2048]
    const unsigned short* __restrict__ demb, // [48][16][512]
    const unsigned short* __restrict__ h0,   // [NL][16][512]
    const float* __restrict__ c0,            // [NL][16][512]
    unsigned short* __restrict__ ds,         // [NL][48][16][512]
    int* __restrict__ flags)                 // [NL][32] stride 16 ints
{
    const int tid = threadIdx.x;
    const int l = blockIdx.x >> 5, p = blockIdx.x & 31;
    const int gate = tid >> 6, lane = tid & 63, q = lane >> 4, ln = lane & 15;
    __shared__ float gsm[4][16][17];
    __shared__ float cbuf[16][17];

    bf16x8 aih[16], ahh[16];
    const size_t row = (size_t)l * 2048 + gate * 512 + p * 16 + ln;
#pragma unroll
    for (int kt = 0; kt < 16; ++kt) aih[kt] = load_w8(Wih + row * 512 + kt * 32 + q * 8);
#pragma unroll
    for (int kt = 0; kt < 16; ++kt) ahh[kt] = load_w8(Whh + row * 512 + kt * 32 + q * 8);
    const float4 bias4 = *(const float4*)(bias + (size_t)l * 2048 + gate * 512 + p * 16 + q * 4);

    const unsigned short* xlayer = (l == 0) ? demb : (ds + (size_t)(l - 1) * SEQ * 16 * 512);
    const int* fin  = flags + (l - 1) * 32 * 16;
    const int* fown = flags + l * 32 * 16;
    int* myflag = flags + (l * 32 + p) * 16;

    for (int t = 0; t < SEQ; ++t) {
        if (tid < 64) {
            if (tid < 32) {
                if (l > 0) {
                    const int* f = fin + tid * 16;
                    int it = 0;
                    while (__hip_atomic_load(f, __ATOMIC_RELAXED, __HIP_MEMORY_SCOPE_AGENT) < t + 1)
                        if (++it > POLLMAX) break;
                }
            } else if (t > 0) {
                const int* f = fown + (tid - 32) * 16;
                int it = 0;
                while (__hip_atomic_load(f, __ATOMIC_RELAXED, __HIP_MEMORY_SCOPE_AGENT) < t)
                    if (++it > POLLMAX) break;
            }
            __builtin_amdgcn_fence(__ATOMIC_ACQUIRE, "agent");
        }
        __syncthreads();

        const unsigned short* xrow = xlayer + ((size_t)t * 16 + ln) * 512;
        const unsigned short* hrow = (t == 0) ? (h0 + ((size_t)l * 16 + ln) * 512)
                                              : (ds + (((size_t)l * SEQ + (t - 1)) * 16 + ln) * 512);
        f32x4 acc0 = {0.f,0.f,0.f,0.f}, acc1 = {0.f,0.f,0.f,0.f};
#pragma unroll
        for (int kt = 0; kt < 16; kt += 2) {
            acc0 = mfma16(aih[kt],     load_b8(xrow + kt * 32 + q * 8),       acc0);
            acc1 = mfma16(aih[kt + 1], load_b8(xrow + (kt + 1) * 32 + q * 8), acc1);
        }
#pragma unroll
        for (int kt = 0; kt < 16; kt += 2) {
            acc0 = mfma16(ahh[kt],     load_b8(hrow + kt * 32 + q * 8),       acc0);
            acc1 = mfma16(ahh[kt + 1], load_b8(hrow + (kt + 1) * 32 + q * 8), acc1);
        }
        gsm[gate][q * 4 + 0][ln] = acc0[0] + acc1[0] + bias4.x;
        gsm[gate][q * 4 + 1][ln] = acc0[1] + acc1[1] + bias4.y;
        gsm[gate][q * 4 + 2][ln] = acc0[2] + acc1[2] + bias4.z;
        gsm[gate][q * 4 + 3][ln] = acc0[3] + acc1[3] + bias4.w;
        __syncthreads();
        if (tid < 128) {
            const int b = tid >> 3, u2 = (tid & 7) * 2;
            unsigned int hv = 0;
#pragma unroll
            for (int s = 0; s < 2; ++s) {
                int u = u2 + s;
                float gi = gsm[0][u][b], gf = gsm[1][u][b], gg = gsm[2][u][b], go = gsm[3][u][b];
                float c = (t == 0) ? c0[((size_t)l * 16 + b) * 512 + p * 16 + u] : cbuf[u][b];
                float cn = sigm(gf) * c + sigm(gi) * tanh_(gg);
                float h = sigm(go) * tanh_(cn);
                cbuf[u][b] = cn;
                hv |= ((unsigned int)f2b(h)) << (16 * s);
            }
            __hip_atomic_store((unsigned int*)(ds + (((size_t)l * SEQ + t) * 16 + b) * 512 + p * 16 + u2),
                               hv, __ATOMIC_RELAXED, __HIP_MEMORY_SCOPE_AGENT);
        }
        __syncthreads();
        if (tid == 0)
            __hip_atomic_store(myflag, t + 1, __ATOMIC_RELEASE, __HIP_MEMORY_SCOPE_AGENT);
    }
}

// ---------------- final projection ----------------
__global__ __launch_bounds__(256) void final_gemm(
    const unsigned short* __restrict__ ds,
    const float* __restrict__ W,
    const float* __restrict__ bias,
    unsigned short* __restrict__ out)
{
    const int tid = threadIdx.x;
    const int w = tid >> 6, lane = tid & 63, q = lane >> 4, ln = lane & 15;
    const int n0 = blockIdx.x * 64;     // 500 blocks
    for (int mb = 0; mb < 12; ++mb) {
        const int m0 = mb * 64 + w * 16;
        bf16x8 afr[16];
#pragma unroll
        for (int kt = 0; kt < 16; ++kt)
            afr[kt] = load_b8(ds + ((size_t)m0 + ln) * 512 + kt * 32 + q * 8);
#pragma unroll
        for (int j = 0; j < 4; ++j) {
            f32x4 acc0 = {0.f,0.f,0.f,0.f}, acc1 = {0.f,0.f,0.f,0.f};
            const float* wb = W + ((size_t)(n0 + j * 16 + ln)) * 512;
#pragma unroll
            for (int kt = 0; kt < 16; kt += 2) {
                bf16x8 b0 = load_w8(wb + kt * 32 + q * 8);
                bf16x8 b1 = load_w8(wb + (kt + 1) * 32 + q * 8);
                acc0 = mfma16(afr[kt], b0, acc0);
                acc1 = mfma16(afr[kt + 1], b1, acc1);
            }
            int n = n0 + j * 16 + ln;
            float bv = bias[n];
#pragma unroll
            for (int r = 0; r < 4; ++r)
                out[((size_t)m0 + q * 4 + r) * NV + n] = f2b(acc0[r] + acc1[r] + bv);
        }
    }
}

// ---------------- transpose: out[b][v][t] (fp32) from ltmp[t*16+b][v] (bf16) ----------------
__global__ __launch_bounds__(256) void transpose_out(
    const unsigned short* __restrict__ tmp, float* __restrict__ out)
{
    __shared__ unsigned short lds[256 * 50];
    const int tid = threadIdx.x;
    const int vb = blockIdx.x % 125, b = blockIdx.x / 125;
    const int v0 = vb * 256;
    for (int tt = 0; tt < SEQ; ++tt)
        lds[tid * 50 + tt] = tmp[((size_t)tt * 16 + b) * NV + v0 + tid];
    __syncthreads();
    float* ob = out + ((size_t)b * NV + v0 + tid) * SEQ;
#pragma unroll
    for (int t4 = 0; t4 < 12; ++t4) {
        float4 v;
        v.x = b2f(lds[tid * 50 + t4 * 4 + 0]);
        v.y = b2f(lds[tid * 50 + t4 * 4 + 1]);
        v.z = b2f(lds[tid * 50 + t4 * 4 + 2]);
        v.w = b2f(lds[tid * 50 + t4 * 4 + 3]);
        *(float4*)(ob + t4 * 4) = v;
    }
}

extern "C" void kernel_launch(void* const* d_in, const int* in_sizes, int n_in,
                              void* d_out, int out_size, void* d_ws, size_t ws_size,
                              hipStream_t stream)
{
    const int*   x       = (const int*)d_in[0];
    const int*   y       = (const int*)d_in[1];
    const float* enc_emb = (const float*)d_in[2];
    const float* enc_Wih = (const float*)d_in[3];
    const float* enc_Whh = (const float*)d_in[4];
    const float* enc_bb  = (const float*)d_in[5];
    const float* dec_emb = (const float*)d_in[6];
    const float* dec_Wih = (const float*)d_in[7];
    const float* dec_Whh = (const float*)d_in[8];
    const float* dec_bb  = (const float*)d_in[9];
    const float* lin_W   = (const float*)d_in[10];
    const float* lin_b   = (const float*)d_in[11];
    float* out = (float*)d_out;

    char* ws = (char*)d_ws;
    int* flags            = (int*)ws;                                  // 64 KB flag area
    unsigned short* demb  = (unsigned short*)(ws + 65536);             // 768 KB
    unsigned short* xsA   = (unsigned short*)(ws + 65536 + 786432);
    unsigned short* xsB   = (unsigned short*)(ws + 65536 + 2 * 786432);
    unsigned short* dech0 = (unsigned short*)(ws + 65536 + 3 * 786432);            // 256 KB
    float* decc0          = (float*)(ws + 65536 + 3 * 786432 + 262144);            // 512 KB
    unsigned short* ds    = (unsigned short*)(ws + 65536 + 3 * 786432 + 262144 + 524288);   // 12 MB
    unsigned short* ltmp  = (unsigned short*)(ws + 65536 + 3 * 786432 + 262144 + 524288 + (size_t)16 * 786432);

    // Gx (12.58 MB) aliases ds (dec_pipe rewrites it later).
    float* Gx = (float*)ds;
    // whhb (enc W_hh bf16, 16.78 MB) aliases ltmp (final_gemm writes it later).
    unsigned short* whhb = ltmp;
    // flag layout (ints): recflag @0 (512), gxflag @512 (4096), decoder flags @8192.
    hipMemsetAsync(flags, 0, 65536, stream);
    embed_kernel<<<1536, 256, 0, stream>>>(x, y, enc_emb, dec_emb, xsA, demb);
    wconv<<<2048, 256, 0, stream>>>(enc_Whh, whhb, NL * 2 * 1024 * 256 / 4);
    enc_v4<<<18, 256, 0, stream>>>(enc_Wih, whhb, enc_bb, xsA, xsB, dech0, decc0,
                                   Gx, flags, flags + 512);
    dec_pipe<<<512, 256, 0, stream>>>(dec_Wih, dec_Whh, dec_bb, demb, dech0, decc0, ds, flags + 8192);
    final_gemm<<<500, 256, 0, stream>>>(ds + (size_t)15 * SEQ * 16 * 512, lin_W, lin_b, ltmp);
    transpose_out<<<2000, 256, 0, stream>>>(ltmp, out);
}

// Round 4
// 6857.306 us; speedup vs baseline: 1.0480x; 1.0480x over previous
//
#include <hip/hip_runtime.h>
#include <stdint.h>

#define SEQ 48
#define NL  16
#define NV  32000
#define POLLMAX 4000000

typedef short bf16x8 __attribute__((ext_vector_type(8)));
typedef float f32x4  __attribute__((ext_vector_type(4)));

__device__ __forceinline__ unsigned short f2b(float f) {
    union { float f; unsigned int u; } v; v.f = f;
    unsigned int r = (v.u + 0x7FFFu + ((v.u >> 16) & 1u)) >> 16;
    return (unsigned short)r;
}
__device__ __forceinline__ float b2f(unsigned short s) {
    union { float f; unsigned int u; } v; v.u = ((unsigned int)s) << 16;
    return v.f;
}
__device__ __forceinline__ bf16x8 load_w8(const float* p) {
    const float4* q = (const float4*)p;
    float4 a = q[0], b = q[1];
    bf16x8 r;
    r[0] = (short)f2b(a.x); r[1] = (short)f2b(a.y);
    r[2] = (short)f2b(a.z); r[3] = (short)f2b(a.w);
    r[4] = (short)f2b(b.x); r[5] = (short)f2b(b.y);
    r[6] = (short)f2b(b.z); r[7] = (short)f2b(b.w);
    return r;
}
__device__ __forceinline__ bf16x8 load_b8(const unsigned short* p) {
    return *(const bf16x8*)p;
}
__device__ __forceinline__ f32x4 mfma16(bf16x8 a, bf16x8 b, f32x4 c) {
    return __builtin_amdgcn_mfma_f32_16x16x32_bf16(a, b, c, 0, 0, 0);
}
__device__ __forceinline__ float sigm(float x) { return 1.0f / (1.0f + __expf(-x)); }
__device__ __forceinline__ float tanh_(float x) { return 1.0f - 2.0f / (__expf(2.0f * x) + 1.0f); }

// ---------------- embeddings: gather + bf16 ----------------
__global__ __launch_bounds__(256) void embed_kernel(
    const int* __restrict__ x, const int* __restrict__ y,
    const float* __restrict__ enc_emb, const float* __restrict__ dec_emb,
    unsigned short* __restrict__ xs, unsigned short* __restrict__ ds)
{
    int bid = blockIdx.x;             // 0..1535
    int which = bid >= 768;
    int r = which ? bid - 768 : bid;
    int t = r >> 4, b = r & 15;
    int tok = which ? y[b * SEQ + t] : x[b * SEQ + t];
    const float* src = (which ? dec_emb : enc_emb) + (size_t)tok * 512;
    unsigned short* dst = (which ? ds : xs) + ((size_t)t * 16 + b) * 512;
    for (int k = threadIdx.x; k < 512; k += 256) dst[k] = f2b(src[k]);
}

// ---------------- W_hh fp32 -> bf16 (once, grid-parallel) ----------------
__global__ __launch_bounds__(256) void wconv(
    const float* __restrict__ src, unsigned short* __restrict__ dst, int n4)
{
    int i = blockIdx.x * 256 + threadIdx.x;
    const int stride = gridDim.x * 256;
    for (; i < n4; i += stride) {
        float4 v = ((const float4*)src)[i];
        uint2 o;
        o.x = (unsigned)f2b(v.x) | ((unsigned)f2b(v.y) << 16);
        o.y = (unsigned)f2b(v.z) | ((unsigned)f2b(v.w) << 16);
        ((uint2*)dst)[i] = o;
    }
}

// ---------------- encoder v5: AGPR-resident Whh via inline-asm MFMA ----------
// 18 WGs x 256 threads, __launch_bounds__(256,1): 1 wave/SIMD -> full 512-reg
// (256 arch + 256 acc) budget per lane.
// bid 0..15 : Stage A producers (unchanged from v4).
// bid 16,17 : recurrence WG per direction. Whh [1024x256] bf16 on ONE CU:
//   kt0..3  -> agw[4][16] in AGPRs (256 acc regs, "a" asm constraints)
//   kt4,kt5(rt<13) -> 29 frags in arch VGPRs (116 regs)
//   kt5(rt>=13),kt6,kt7 -> 35 frag-groups in 140 KB LDS
// MFMA via inline asm (A operand from AGPR is legal on gfx950, isa §10).
// Round-3 failure: compiler caps arch VGPRs at 256 and spills to scratch
// instead of AGPRs (VGPR_Count=256, WRITE_SIZE=210MB). "a" constraints make
// AGPR placement deterministic.

__global__ __launch_bounds__(256, 1) void enc_v5(
    const float* __restrict__ Wih,             // [NL][2][1024][512] fp32
    const unsigned short* __restrict__ whhb,   // [NL][2][1024][256] bf16
    const float* __restrict__ bias,            // [NL][2][1024]
    unsigned short* __restrict__ xsA, unsigned short* __restrict__ xsB, // [48][16][512]
    unsigned short* __restrict__ dec_h0,       // [NL][16][512] bf16
    float* __restrict__ dec_c0,                // [NL][16][512] fp32
    float* __restrict__ Gx,                    // [2 par][2 dir][48][16][1024] fp32
    int* __restrict__ recflag,                 // [NL][2] stride 16 ints
    int* __restrict__ gxflag)                  // [NL][2][8] stride 16 ints
{
    const int tid = threadIdx.x, bid = blockIdx.x;
    const int wv = tid >> 6, lane = tid & 63, q = lane >> 4, ln = lane & 15;

    // LDS: 143,360 B weight/x_sh union + 16,896 B h double-buffer = 160,256 B
    __shared__ __align__(16) char smem_u[35 * 4096];
    __shared__ unsigned short h_lds2[2][16][264];

    if (bid < 16) {
        // ================= Stage A: input-GEMM producers (as v4) ==============
        const int dir = bid >> 3, pblk = bid & 7;
        const int cb = tid >> 4, cc = tid & 15;
        unsigned short (*x_sh)[528] = (unsigned short (*)[528])smem_u;
        for (int l = 0; l < NL; ++l) {
            bf16x8 aih[2][16];
            float4 bias4[2];
#pragma unroll
            for (int rt = 0; rt < 2; ++rt) {
                const int row0 = wv * 256 + pblk * 32 + rt * 16;
                const float* wb = Wih + (((size_t)(l * 2 + dir) * 1024) + row0 + ln) * 512;
#pragma unroll
                for (int kt = 0; kt < 16; ++kt) aih[rt][kt] = load_w8(wb + kt * 32 + q * 8);
                bias4[rt] = *(const float4*)(bias + (size_t)(l * 2 + dir) * 1024 + row0 + q * 4);
            }
            const unsigned short* xin = (l & 1) ? xsB : xsA;
            float* gxl = Gx + (size_t)((l & 1) * 2 + dir) * SEQ * 16 * 1024;
            int* myflag = gxflag + ((l * 2 + dir) * 8 + pblk) * 16;
            const int* rfprev = recflag + (l - 1) * 2 * 16;
            int seen = 0;
            for (int s = 0; s < SEQ; ++s) {
                const int t_src = dir ? (SEQ - 1 - s) : s;
                if (l > 0) {
                    // xs_l[t_src] full <=> own-dir rec(l-1) >= s+1 AND other >= 48-s
                    if (tid < 64) {
                        if (tid < 2) {
                            const int need = (tid == dir) ? (s + 1) : (SEQ - s);
                            if (seen < need) {
                                const int* f = rfprev + tid * 16;
                                int v = __hip_atomic_load(f, __ATOMIC_RELAXED, __HIP_MEMORY_SCOPE_AGENT);
                                int it = 0;
                                while (v < need && ++it <= POLLMAX)
                                    v = __hip_atomic_load(f, __ATOMIC_RELAXED, __HIP_MEMORY_SCOPE_AGENT);
                                seen = v;
                            }
                        }
                        __builtin_amdgcn_fence(__ATOMIC_ACQUIRE, "agent");
                    }
                    __syncthreads();
                }
                // stage x row into LDS
                {
                    const unsigned short* sr = xin + ((size_t)t_src * 16 + cb) * 512 + cc * 32;
#pragma unroll
                    for (int j = 0; j < 4; ++j)
                        *(bf16x8*)&x_sh[cb][cc * 32 + j * 8] = load_b8(sr + j * 8);
                }
                __syncthreads();
                f32x4 a0 = {0.f,0.f,0.f,0.f}, a1 = {0.f,0.f,0.f,0.f};
                f32x4 b0 = {0.f,0.f,0.f,0.f}, b1 = {0.f,0.f,0.f,0.f};
#pragma unroll
                for (int kt = 0; kt < 16; kt += 2) {
                    bf16x8 x0 = load_b8(&x_sh[ln][kt * 32 + q * 8]);
                    bf16x8 x1 = load_b8(&x_sh[ln][(kt + 1) * 32 + q * 8]);
                    a0 = mfma16(aih[0][kt],     x0, a0);
                    a1 = mfma16(aih[0][kt + 1], x1, a1);
                    b0 = mfma16(aih[1][kt],     x0, b0);
                    b1 = mfma16(aih[1][kt + 1], x1, b1);
                }
#pragma unroll
                for (int rt = 0; rt < 2; ++rt) {
                    const int row0 = wv * 256 + pblk * 32 + rt * 16;
                    float g0 = (rt ? b0[0] : a0[0]) + (rt ? b1[0] : a1[0]) + ((const float*)&bias4[rt])[0];
                    float g1 = (rt ? b0[1] : a0[1]) + (rt ? b1[1] : a1[1]) + ((const float*)&bias4[rt])[1];
                    float g2 = (rt ? b0[2] : a0[2]) + (rt ? b1[2] : a1[2]) + ((const float*)&bias4[rt])[2];
                    float g3 = (rt ? b0[3] : a0[3]) + (rt ? b1[3] : a1[3]) + ((const float*)&bias4[rt])[3];
                    unsigned long long u0 = (unsigned long long)__float_as_uint(g0) |
                                            ((unsigned long long)__float_as_uint(g1) << 32);
                    unsigned long long u1 = (unsigned long long)__float_as_uint(g2) |
                                            ((unsigned long long)__float_as_uint(g3) << 32);
                    unsigned long long* gd =
                        (unsigned long long*)(gxl + ((size_t)t_src * 16 + ln) * 1024 + row0 + q * 4);
                    __hip_atomic_store(gd,     u0, __ATOMIC_RELAXED, __HIP_MEMORY_SCOPE_AGENT);
                    __hip_atomic_store(gd + 1, u1, __ATOMIC_RELAXED, __HIP_MEMORY_SCOPE_AGENT);
                }
                __syncthreads();   // x_sh reads done before next chunk's writes
                if (tid == 0)
                    __hip_atomic_store(myflag, s + 1, __ATOMIC_RELEASE, __HIP_MEMORY_SCOPE_AGENT);
            }
        }
        return;
    }

    // ================= recurrence: one WG (4 waves) per direction =================
    const int dir = bid - 16;
    // LDS frag groups: kt6 -> g=rt (0..15); kt7 -> g=16+rt; kt5 rt>=13 -> g=32+(rt-13)
#define LDSFRAG(g) load_b8((const unsigned short*)(smem_u + (g) * 4096 + tid * 16))
    // inline-asm MFMA: D,C tied in VGPRs; A from AGPR ("a") or VGPR ("v"); B VGPR.
#define MFMA_AG(accv, w, h) asm volatile("v_mfma_f32_16x16x32_bf16 %0, %1, %2, %0" \
                                         : "+v"(accv) : "a"(w), "v"(h))
#define MFMA_VG(accv, w, h) asm volatile("v_mfma_f32_16x16x32_bf16 %0, %1, %2, %0" \
                                         : "+v"(accv) : "v"(w), "v"(h))

    f32x4 cr[4];
    for (int l = 0; l < NL; ++l) {
        __syncthreads();   // prior layer's LDS-frag reads done before overwrite
        bf16x8 agw[4][16];   // [kt][rt], kt0..3 -> AGPRs (only "a" uses)
        bf16x8 wv4[16];      // kt4
        bf16x8 wv5[13];      // kt5, rt<13
        {
            const unsigned short* wbase = whhb + (size_t)(l * 2 + dir) * 262144;
#pragma unroll
            for (int rt = 0; rt < 16; ++rt) {
                const int row = (rt >> 2) * 256 + wv * 64 + (rt & 3) * 16 + ln;
                const unsigned short* rp = wbase + (size_t)row * 256 + q * 8;
#pragma unroll
                for (int kt = 0; kt < 4; ++kt) agw[kt][rt] = load_b8(rp + kt * 32);
                wv4[rt] = load_b8(rp + 4 * 32);
                if (rt < 13) wv5[rt] = load_b8(rp + 5 * 32);
                else *(bf16x8*)(smem_u + (32 + rt - 13) * 4096 + tid * 16) = load_b8(rp + 5 * 32);
                *(bf16x8*)(smem_u + rt * 4096 + tid * 16)        = load_b8(rp + 6 * 32);
                *(bf16x8*)(smem_u + (16 + rt) * 4096 + tid * 16) = load_b8(rp + 7 * 32);
            }
        }
        const int* gxf = gxflag + (l * 2 + dir) * 8 * 16;
        int* rf = recflag + (l * 2 + dir) * 16;
        const float* gxl = Gx + (size_t)((l & 1) * 2 + dir) * SEQ * 16 * 1024;
        unsigned short* xout = (l & 1) ? xsA : xsB;
        int seen = 0;

        for (int t = 0; t < SEQ; ++t) {
            const int t_src = dir ? (SEQ - 1 - t) : t;
            // wait Gx chunk t from this direction's 8 producers (value-cached)
            if (tid < 64) {
                if (tid < 8 && seen < t + 1) {
                    const int* f = gxf + tid * 16;
                    int v = __hip_atomic_load(f, __ATOMIC_RELAXED, __HIP_MEMORY_SCOPE_AGENT);
                    int it = 0;
                    while (v < t + 1 && ++it <= POLLMAX)
                        v = __hip_atomic_load(f, __ATOMIC_RELAXED, __HIP_MEMORY_SCOPE_AGENT);
                    seen = v;
                }
                __builtin_amdgcn_fence(__ATOMIC_ACQUIRE, "agent");
            }
            __syncthreads();   // h_lds2 writes of t-1 visible; weight LDS/AGPRs ready
            if (tid == 0 && t > 0)
                __hip_atomic_store(rf, t, __ATOMIC_RELEASE, __HIP_MEMORY_SCOPE_AGENT);

            const unsigned short* hcur = &h_lds2[t & 1][0][0];
            unsigned short*       hnxt = &h_lds2[(t + 1) & 1][0][0];
            const float* gxt = gxl + ((size_t)t_src * 16 + ln) * 1024;

            bf16x8 hfr[8];
            if (t > 0) {
#pragma unroll
                for (int kt = 0; kt < 8; ++kt)
                    hfr[kt] = load_b8(hcur + ln * 264 + kt * 32 + q * 8);
            }

#pragma unroll
            for (int ph = 0; ph < 2; ++ph) {
                f32x4 acc[8];
#pragma unroll
                for (int a = 0; a < 8; ++a) acc[a] = (f32x4){0.f, 0.f, 0.f, 0.f};
                if (t > 0) {
                    asm volatile("s_nop 3" ::);   // VALU acc-init -> MFMA SrcC wait
#pragma unroll
                    for (int kt = 0; kt < 8; ++kt) {
#pragma unroll
                        for (int gate = 0; gate < 4; ++gate) {
#pragma unroll
                            for (int s = 0; s < 2; ++s) {
                                const int rt = gate * 4 + ph * 2 + s;
                                const int ai = gate * 2 + s;
                                if (kt < 4) {
                                    MFMA_AG(acc[ai], agw[kt][rt], hfr[kt]);
                                } else if (kt == 4) {
                                    MFMA_VG(acc[ai], wv4[rt], hfr[kt]);
                                } else if (kt == 5) {
                                    if (rt < 13) { MFMA_VG(acc[ai], wv5[rt], hfr[kt]); }
                                    else { bf16x8 wl = LDSFRAG(32 + rt - 13); MFMA_VG(acc[ai], wl, hfr[kt]); }
                                } else if (kt == 6) {
                                    bf16x8 wl = LDSFRAG(rt); MFMA_VG(acc[ai], wl, hfr[kt]);
                                } else {
                                    bf16x8 wl = LDSFRAG(16 + rt); MFMA_VG(acc[ai], wl, hfr[kt]);
                                }
                            }
                        }
                    }
                    asm volatile("s_nop 7\n\ts_nop 7" ::);  // MFMA DstD -> VALU read wait
                }
                // epilogue: add Gx, lane-local LSTM update
#pragma unroll
                for (int s = 0; s < 2; ++s) {
                    const int u16i = ph * 2 + s;
                    const int ubase = wv * 64 + u16i * 16 + q * 4;
                    float4 gxi  = *(const float4*)(gxt + 0 * 256 + ubase);
                    float4 gxf4 = *(const float4*)(gxt + 1 * 256 + ubase);
                    float4 gxg  = *(const float4*)(gxt + 2 * 256 + ubase);
                    float4 gxo  = *(const float4*)(gxt + 3 * 256 + ubase);
                    unsigned short hb[4];
#pragma unroll
                    for (int r = 0; r < 4; ++r) {
                        float gi = acc[0 + s][r] + ((const float*)&gxi)[r];
                        float gf = acc[2 + s][r] + ((const float*)&gxf4)[r];
                        float gg = acc[4 + s][r] + ((const float*)&gxg)[r];
                        float go = acc[6 + s][r] + ((const float*)&gxo)[r];
                        float c  = (t == 0) ? 0.f : cr[u16i][r];
                        float cn = sigm(gf) * c + sigm(gi) * tanh_(gg);
                        cr[u16i][r] = cn;
                        hb[r] = f2b(sigm(go) * tanh_(cn));
                    }
                    uint2 hv;
                    hv.x = (unsigned)hb[0] | ((unsigned)hb[1] << 16);
                    hv.y = (unsigned)hb[2] | ((unsigned)hb[3] << 16);
                    *(uint2*)(hnxt + ln * 264 + ubase) = hv;
                    unsigned long long hl = (unsigned long long)hv.x | ((unsigned long long)hv.y << 32);
                    __hip_atomic_store(
                        (unsigned long long*)(xout + ((size_t)t_src * 16 + ln) * 512 + dir * 256 + ubase),
                        hl, __ATOMIC_RELAXED, __HIP_MEMORY_SCOPE_AGENT);
                    if (t == SEQ - 1) {
                        *(uint2*)(dec_h0 + ((size_t)l * 16 + ln) * 512 + dir * 256 + ubase) = hv;
                        float4 cv;
                        cv.x = cr[u16i][0]; cv.y = cr[u16i][1];
                        cv.z = cr[u16i][2]; cv.w = cr[u16i][3];
                        *(float4*)(dec_c0 + ((size_t)l * 16 + ln) * 512 + dir * 256 + ubase) = cv;
                    }
                }
            }
        }
        __syncthreads();
        if (tid == 0)
            __hip_atomic_store(rf, SEQ, __ATOMIC_RELEASE, __HIP_MEMORY_SCOPE_AGENT);
    }
#undef LDSFRAG
#undef MFMA_AG
#undef MFMA_VG
}

// ---------------- pipelined decoder: ALL 16 layers concurrent, 512 WGs ----------------
__global__ __launch_bounds__(256, 2) void dec_pipe(
    const float* __restrict__ Wih,   // [NL][2048][512]
    const float* __restrict__ Whh,   // [NL][2048][512]
    const float* __restrict__ bias,  // [NL][2048]
    const unsigned short* __restrict__ demb, // [48][16][512]
    const unsigned short* __restrict__ h0,   // [NL][16][512]
    const float* __restrict__ c0,            // [NL][16][512]
    unsigned short* __restrict__ ds,         // [NL][48][16][512]
    int* __restrict__ flags)                 // [NL][32] stride 16 ints
{
    const int tid = threadIdx.x;
    const int l = blockIdx.x >> 5, p = blockIdx.x & 31;
    const int gate = tid >> 6, lane = tid & 63, q = lane >> 4, ln = lane & 15;
    __shared__ float gsm[4][16][17];
    __shared__ float cbuf[16][17];

    bf16x8 aih[16], ahh[16];
    const size_t row = (size_t)l * 2048 + gate * 512 + p * 16 + ln;
#pragma unroll
    for (int kt = 0; kt < 16; ++kt) aih[kt] = load_w8(Wih + row * 512 + kt * 32 + q * 8);
#pragma unroll
    for (int kt = 0; kt < 16; ++kt) ahh[kt] = load_w8(Whh + row * 512 + kt * 32 + q * 8);
    const float4 bias4 = *(const float4*)(bias + (size_t)l * 2048 + gate * 512 + p * 16 + q * 4);

    const unsigned short* xlayer = (l == 0) ? demb : (ds + (size_t)(l - 1) * SEQ * 16 * 512);
    const int* fin  = flags + (l - 1) * 32 * 16;
    const int* fown = flags + l * 32 * 16;
    int* myflag = flags + (l * 32 + p) * 16;

    for (int t = 0; t < SEQ; ++t) {
        if (tid < 64) {
            if (tid < 32) {
                if (l > 0) {
                    const int* f = fin + tid * 16;
                    int it = 0;
                    while (__hip_atomic_load(f, __ATOMIC_RELAXED, __HIP_MEMORY_SCOPE_AGENT) < t + 1)
                        if (++it > POLLMAX) break;
                }
            } else if (t > 0) {
                const int* f = fown + (tid - 32) * 16;
                int it = 0;
                while (__hip_atomic_load(f, __ATOMIC_RELAXED, __HIP_MEMORY_SCOPE_AGENT) < t)
                    if (++it > POLLMAX) break;
            }
            __builtin_amdgcn_fence(__ATOMIC_ACQUIRE, "agent");
        }
        __syncthreads();

        const unsigned short* xrow = xlayer + ((size_t)t * 16 + ln) * 512;
        const unsigned short* hrow = (t == 0) ? (h0 + ((size_t)l * 16 + ln) * 512)
                                              : (ds + (((size_t)l * SEQ + (t - 1)) * 16 + ln) * 512);
        f32x4 acc0 = {0.f,0.f,0.f,0.f}, acc1 = {0.f,0.f,0.f,0.f};
#pragma unroll
        for (int kt = 0; kt < 16; kt += 2) {
            acc0 = mfma16(aih[kt],     load_b8(xrow + kt * 32 + q * 8),       acc0);
            acc1 = mfma16(aih[kt + 1], load_b8(xrow + (kt + 1) * 32 + q * 8), acc1);
        }
#pragma unroll
        for (int kt = 0; kt < 16; kt += 2) {
            acc0 = mfma16(ahh[kt],     load_b8(hrow + kt * 32 + q * 8),       acc0);
            acc1 = mfma16(ahh[kt + 1], load_b8(hrow + (kt + 1) * 32 + q * 8), acc1);
        }
        gsm[gate][q * 4 + 0][ln] = acc0[0] + acc1[0] + bias4.x;
        gsm[gate][q * 4 + 1][ln] = acc0[1] + acc1[1] + bias4.y;
        gsm[gate][q * 4 + 2][ln] = acc0[2] + acc1[2] + bias4.z;
        gsm[gate][q * 4 + 3][ln] = acc0[3] + acc1[3] + bias4.w;
        __syncthreads();
        if (tid < 128) {
            const int b = tid >> 3, u2 = (tid & 7) * 2;
            unsigned int hv = 0;
#pragma unroll
            for (int s = 0; s < 2; ++s) {
                int u = u2 + s;
                float gi = gsm[0][u][b], gf = gsm[1][u][b], gg = gsm[2][u][b], go = gsm[3][u][b];
                float c = (t == 0) ? c0[((size_t)l * 16 + b) * 512 + p * 16 + u] : cbuf[u][b];
                float cn = sigm(gf) * c + sigm(gi) * tanh_(gg);
                float h = sigm(go) * tanh_(cn);
                cbuf[u][b] = cn;
                hv |= ((unsigned int)f2b(h)) << (16 * s);
            }
            __hip_atomic_store((unsigned int*)(ds + (((size_t)l * SEQ + t) * 16 + b) * 512 + p * 16 + u2),
                               hv, __ATOMIC_RELAXED, __HIP_MEMORY_SCOPE_AGENT);
        }
        __syncthreads();
        if (tid == 0)
            __hip_atomic_store(myflag, t + 1, __ATOMIC_RELEASE, __HIP_MEMORY_SCOPE_AGENT);
    }
}

// ---------------- final projection ----------------
__global__ __launch_bounds__(256) void final_gemm(
    const unsigned short* __restrict__ ds,
    const float* __restrict__ W,
    const float* __restrict__ bias,
    unsigned short* __restrict__ out)
{
    const int tid = threadIdx.x;
    const int w = tid >> 6, lane = tid & 63, q = lane >> 4, ln = lane & 15;
    const int n0 = blockIdx.x * 64;     // 500 blocks
    for (int mb = 0; mb < 12; ++mb) {
        const int m0 = mb * 64 + w * 16;
        bf16x8 afr[16];
#pragma unroll
        for (int kt = 0; kt < 16; ++kt)
            afr[kt] = load_b8(ds + ((size_t)m0 + ln) * 512 + kt * 32 + q * 8);
#pragma unroll
        for (int j = 0; j < 4; ++j) {
            f32x4 acc0 = {0.f,0.f,0.f,0.f}, acc1 = {0.f,0.f,0.f,0.f};
            const float* wb = W + ((size_t)(n0 + j * 16 + ln)) * 512;
#pragma unroll
            for (int kt = 0; kt < 16; kt += 2) {
                bf16x8 b0 = load_w8(wb + kt * 32 + q * 8);
                bf16x8 b1 = load_w8(wb + (kt + 1) * 32 + q * 8);
                acc0 = mfma16(afr[kt], b0, acc0);
                acc1 = mfma16(afr[kt + 1], b1, acc1);
            }
            int n = n0 + j * 16 + ln;
            float bv = bias[n];
#pragma unroll
            for (int r = 0; r < 4; ++r)
                out[((size_t)m0 + q * 4 + r) * NV + n] = f2b(acc0[r] + acc1[r] + bv);
        }
    }
}

// ---------------- transpose: out[b][v][t] (fp32) from ltmp[t*16+b][v] (bf16) ----------------
__global__ __launch_bounds__(256) void transpose_out(
    const unsigned short* __restrict__ tmp, float* __restrict__ out)
{
    __shared__ unsigned short lds[256 * 50];
    const int tid = threadIdx.x;
    const int vb = blockIdx.x % 125, b = blockIdx.x / 125;
    const int v0 = vb * 256;
    for (int tt = 0; tt < SEQ; ++tt)
        lds[tid * 50 + tt] = tmp[((size_t)tt * 16 + b) * NV + v0 + tid];
    __syncthreads();
    float* ob = out + ((size_t)b * NV + v0 + tid) * SEQ;
#pragma unroll
    for (int t4 = 0; t4 < 12; ++t4) {
        float4 v;
        v.x = b2f(lds[tid * 50 + t4 * 4 + 0]);
        v.y = b2f(lds[tid * 50 + t4 * 4 + 1]);
        v.z = b2f(lds[tid * 50 + t4 * 4 + 2]);
        v.w = b2f(lds[tid * 50 + t4 * 4 + 3]);
        *(float4*)(ob + t4 * 4) = v;
    }
}

extern "C" void kernel_launch(void* const* d_in, const int* in_sizes, int n_in,
                              void* d_out, int out_size, void* d_ws, size_t ws_size,
                              hipStream_t stream)
{
    const int*   x       = (const int*)d_in[0];
    const int*   y       = (const int*)d_in[1];
    const float* enc_emb = (const float*)d_in[2];
    const float* enc_Wih = (const float*)d_in[3];
    const float* enc_Whh = (const float*)d_in[4];
    const float* enc_bb  = (const float*)d_in[5];
    const float* dec_emb = (const float*)d_in[6];
    const float* dec_Wih = (const float*)d_in[7];
    const float* dec_Whh = (const float*)d_in[8];
    const float* dec_bb  = (const float*)d_in[9];
    const float* lin_W   = (const float*)d_in[10];
    const float* lin_b   = (const float*)d_in[11];
    float* out = (float*)d_out;

    char* ws = (char*)d_ws;
    int* flags            = (int*)ws;                                  // 64 KB flag area
    unsigned short* demb  = (unsigned short*)(ws + 65536);             // 768 KB
    unsigned short* xsA   = (unsigned short*)(ws + 65536 + 786432);
    unsigned short* xsB   = (unsigned short*)(ws + 65536 + 2 * 786432);
    unsigned short* dech0 = (unsigned short*)(ws + 65536 + 3 * 786432);            // 256 KB
    float* decc0          = (float*)(ws + 65536 + 3 * 786432 + 262144);            // 512 KB
    unsigned short* ds    = (unsigned short*)(ws + 65536 + 3 * 786432 + 262144 + 524288);   // 12 MB
    unsigned short* ltmp  = (unsigned short*)(ws + 65536 + 3 * 786432 + 262144 + 524288 + (size_t)16 * 786432);

    // Gx (12.58 MB) aliases ds (dec_pipe rewrites it later).
    float* Gx = (float*)ds;
    // whhb (enc W_hh bf16, 16.78 MB) aliases ltmp (final_gemm writes it later).
    unsigned short* whhb = ltmp;
    // flag layout (ints): recflag @0 (512), gxflag @512 (4096), decoder flags @8192.
    hipMemsetAsync(flags, 0, 65536, stream);
    embed_kernel<<<1536, 256, 0, stream>>>(x, y, enc_emb, dec_emb, xsA, demb);
    wconv<<<2048, 256, 0, stream>>>(enc_Whh, whhb, NL * 2 * 1024 * 256 / 4);
    enc_v5<<<18, 256, 0, stream>>>(enc_Wih, whhb, enc_bb, xsA, xsB, dech0, decc0,
                                   Gx, flags, flags + 512);
    dec_pipe<<<512, 256, 0, stream>>>(dec_Wih, dec_Whh, dec_bb, demb, dech0, decc0, ds, flags + 8192);
    final_gemm<<<500, 256, 0, stream>>>(ds + (size_t)15 * SEQ * 16 * 512, lin_W, lin_b, ltmp);
    transpose_out<<<2000, 256, 0, stream>>>(ltmp, out);
}